// Round 1
// baseline (422.316 us; speedup 1.0000x reference)
//
#include <hip/hip_runtime.h>

typedef __attribute__((ext_vector_type(8))) short bf16x8;
typedef __attribute__((ext_vector_type(4))) float f32x4;

#define NTOK 262144   // 64^3 tokens
#define NWIN 4096     // 16^3 windows of 4^3

__device__ __forceinline__ unsigned short f2bf(float f) {
    unsigned int u = __float_as_uint(f);
    unsigned int r = (u + 0x7FFFu + ((u >> 16) & 1u)) >> 16;
    return (unsigned short)r;
}
__device__ __forceinline__ float bf2f(unsigned short u) {
    return __uint_as_float(((unsigned int)u) << 16);
}
__device__ __forceinline__ int region(int g) { return (g >= 60) + (g >= 62); }

// ---------------- K0: weight convert + transpose to N-major bf16 ----------------
__global__ void convert_weights(const float* __restrict__ Wqkv, const float* __restrict__ Wout,
                                const float* __restrict__ W1, const float* __restrict__ W2,
                                unsigned short* __restrict__ wq_t, unsigned short* __restrict__ wo_t,
                                unsigned short* __restrict__ w1_t, unsigned short* __restrict__ w2_t) {
    int idx = blockIdx.x * blockDim.x + threadIdx.x;
    if (idx < 27648) {                       // wq_t[288][96] = Wqkv[96][288]^T
        int n = idx / 96, k = idx % 96;
        wq_t[idx] = f2bf(Wqkv[k * 288 + n]);
    } else if (idx < 27648 + 9216) {         // wo_t[96][96]
        int i = idx - 27648; int n = i / 96, k = i % 96;
        wo_t[i] = f2bf(Wout[k * 96 + n]);
    } else if (idx < 27648 + 9216 + 36864) { // w1_t[384][96]
        int i = idx - 36864; int n = i / 96, k = i % 96;
        w1_t[i] = f2bf(W1[k * 384 + n]);
    } else if (idx < 110592) {               // w2_t[96][384]
        int i = idx - 73728; int n = i / 384, k = i % 384;
        w2_t[i] = f2bf(W2[k * 96 + n]);
    }
}

// ---------------- K1: LN1 + cyclic shift(-2) + window-major relayout ----------------
__global__ __launch_bounds__(256) void ln1_shift_kernel(const float* __restrict__ x,
                                                        const float* __restrict__ g,
                                                        const float* __restrict__ b,
                                                        unsigned short* __restrict__ y) {
    int tid = blockIdx.x * blockDim.x + threadIdx.x;
    int token = tid >> 5;          // output (shifted-frame) token
    int lane = tid & 31;
    if (token >= NTOK) return;
    int pz = token & 63, py = (token >> 6) & 63, px = token >> 12;
    int sx = (px + 2) & 63, sy = (py + 2) & 63, sz = (pz + 2) & 63;   // roll(x,-2)
    size_t src = ((size_t)((sx * 64 + sy) * 64 + sz)) * 96;
    float v0 = x[src + lane], v1 = x[src + 32 + lane], v2 = x[src + 64 + lane];
    float s = v0 + v1 + v2;
    float sq = v0 * v0 + v1 * v1 + v2 * v2;
    #pragma unroll
    for (int m = 16; m >= 1; m >>= 1) { s += __shfl_xor(s, m, 32); sq += __shfl_xor(sq, m, 32); }
    float mean = s * (1.0f / 96.0f);
    float var = sq * (1.0f / 96.0f) - mean * mean;
    float rstd = rsqrtf(var + 1e-5f);
    int win = ((px >> 2) * 16 + (py >> 2)) * 16 + (pz >> 2);
    int loc = ((px & 3) * 4 + (py & 3)) * 4 + (pz & 3);
    size_t dst = ((size_t)(win * 64 + loc)) * 96;
    y[dst + lane]      = f2bf((v0 - mean) * rstd * g[lane]      + b[lane]);
    y[dst + 32 + lane] = f2bf((v1 - mean) * rstd * g[lane + 32] + b[lane + 32]);
    y[dst + 64 + lane] = f2bf((v2 - mean) * rstd * g[lane + 64] + b[lane + 64]);
}

// ---------------- K2: QKV GEMM  [262144,96] x [96,288] -> qkv[win][qq][h][tok][32] bf16 ----------------
__global__ __launch_bounds__(384) void qkv_gemm_kernel(const unsigned short* __restrict__ y,
                                                       const unsigned short* __restrict__ wq_t,
                                                       unsigned short* __restrict__ qkv) {
    int win = blockIdx.x;
    int wave = threadIdx.x >> 6;
    int lane = threadIdx.x & 63;
    int lr = lane & 15, kh = lane >> 4;
    f32x4 acc[4][3];
    #pragma unroll
    for (int m = 0; m < 4; ++m)
        #pragma unroll
        for (int n = 0; n < 3; ++n) acc[m][n] = (f32x4){0.f, 0.f, 0.f, 0.f};
    #pragma unroll
    for (int ks = 0; ks < 3; ++ks) {
        int k0 = ks * 32;
        bf16x8 a[4], bb[3];
        #pragma unroll
        for (int m = 0; m < 4; ++m)
            a[m] = *(const bf16x8*)(y + ((size_t)win * 64 + m * 16 + lr) * 96 + k0 + kh * 8);
        #pragma unroll
        for (int n = 0; n < 3; ++n)
            bb[n] = *(const bf16x8*)(wq_t + ((size_t)(wave * 48 + n * 16 + lr)) * 96 + k0 + kh * 8);
        #pragma unroll
        for (int m = 0; m < 4; ++m)
            #pragma unroll
            for (int n = 0; n < 3; ++n)
                acc[m][n] = __builtin_amdgcn_mfma_f32_16x16x32_bf16(a[m], bb[n], acc[m][n], 0, 0, 0);
    }
    #pragma unroll
    for (int n = 0; n < 3; ++n) {
        int c = wave * 48 + n * 16 + lr;
        int qq = c / 96, rem = c % 96;
        int h = rem >> 5, d = rem & 31;
        size_t base = (((size_t)win * 3 + qq) * 3 + h) * 2048 + d;
        #pragma unroll
        for (int m = 0; m < 4; ++m)
            #pragma unroll
            for (int r = 0; r < 4; ++r) {
                int tok = m * 16 + kh * 4 + r;
                qkv[base + (size_t)tok * 32] = f2bf(acc[m][n][r]);
            }
    }
}

// ---------------- K3: per-window attention ----------------
__global__ __launch_bounds__(192) void attn_kernel(const unsigned short* __restrict__ qkv,
                                                   const float* __restrict__ pos_tab,
                                                   unsigned short* __restrict__ a_out) {
    __shared__ __align__(16) float pos[344];
    __shared__ __align__(16) unsigned short vT[3][32][72];
    __shared__ __align__(16) unsigned short P[3][64][72];
    int win = blockIdx.x;
    int h = threadIdx.x >> 6;
    int lane = threadIdx.x & 63;
    int lr = lane & 15, kh = lane >> 4;
    for (int i = threadIdx.x; i < 343; i += 192) pos[i] = pos_tab[i];
    // load V transposed into LDS
    size_t vbase = (((size_t)win * 3 + 2) * 3 + h) * 2048;
    #pragma unroll
    for (int i = 0; i < 8; ++i) {
        int e0 = i * 256 + lane * 4;
        int tok = e0 >> 5, d = e0 & 31;
        const unsigned short* p = qkv + vbase + e0;
        vT[h][d + 0][tok] = p[0]; vT[h][d + 1][tok] = p[1];
        vT[h][d + 2][tok] = p[2]; vT[h][d + 3][tok] = p[3];
    }
    __syncthreads();
    // QK^T
    size_t qbase = (((size_t)win * 3 + 0) * 3 + h) * 2048;
    size_t kbase = (((size_t)win * 3 + 1) * 3 + h) * 2048;
    f32x4 acc[4][4];
    #pragma unroll
    for (int m = 0; m < 4; ++m)
        #pragma unroll
        for (int n = 0; n < 4; ++n) acc[m][n] = (f32x4){0.f, 0.f, 0.f, 0.f};
    bf16x8 aq[4], bk[4];
    #pragma unroll
    for (int m = 0; m < 4; ++m) aq[m] = *(const bf16x8*)(qkv + qbase + (m * 16 + lr) * 32 + kh * 8);
    #pragma unroll
    for (int n = 0; n < 4; ++n) bk[n] = *(const bf16x8*)(qkv + kbase + (n * 16 + lr) * 32 + kh * 8);
    #pragma unroll
    for (int m = 0; m < 4; ++m)
        #pragma unroll
        for (int n = 0; n < 4; ++n)
            acc[m][n] = __builtin_amdgcn_mfma_f32_16x16x32_bf16(aq[m], bk[n], acc[m][n], 0, 0, 0);
    // scale + relative-position bias + shifted-window mask
    int ix = win >> 8, iy = (win >> 4) & 15, iz = win & 15;
    const float scale = 0.17677669529663689f;  // 32^-0.5
    #pragma unroll
    for (int n = 0; n < 4; ++n) {
        int j = n * 16 + lr;
        int jwx = j >> 4, jwy = (j >> 2) & 3, jwz = j & 3;
        int labj = 9 * region(ix * 4 + jwx) + 3 * region(iy * 4 + jwy) + region(iz * 4 + jwz);
        #pragma unroll
        for (int m = 0; m < 4; ++m)
            #pragma unroll
            for (int r = 0; r < 4; ++r) {
                int i = m * 16 + kh * 4 + r;
                int iwx = i >> 4, iwy = (i >> 2) & 3, iwz = i & 3;
                int labi = 9 * region(ix * 4 + iwx) + 3 * region(iy * 4 + iwy) + region(iz * 4 + iwz);
                float bias = pos[((iwx - jwx + 3) * 7 + (iwy - jwy + 3)) * 7 + (iwz - jwz + 3)];
                acc[m][n][r] = acc[m][n][r] * scale + bias + (labi != labj ? -1e9f : 0.0f);
            }
    }
    // softmax over rows (row lives in 16 lanes x 4 n-frags)
    #pragma unroll
    for (int m = 0; m < 4; ++m)
        #pragma unroll
        for (int r = 0; r < 4; ++r) {
            float mx = fmaxf(fmaxf(acc[m][0][r], acc[m][1][r]), fmaxf(acc[m][2][r], acc[m][3][r]));
            #pragma unroll
            for (int s = 1; s < 16; s <<= 1) mx = fmaxf(mx, __shfl_xor(mx, s, 16));
            float e0 = __expf(acc[m][0][r] - mx), e1 = __expf(acc[m][1][r] - mx);
            float e2 = __expf(acc[m][2][r] - mx), e3 = __expf(acc[m][3][r] - mx);
            float sum = e0 + e1 + e2 + e3;
            #pragma unroll
            for (int s = 1; s < 16; s <<= 1) sum += __shfl_xor(sum, s, 16);
            float rs = 1.0f / sum;
            acc[m][0][r] = e0 * rs; acc[m][1][r] = e1 * rs;
            acc[m][2][r] = e2 * rs; acc[m][3][r] = e3 * rs;
        }
    // write P to LDS (bf16)
    #pragma unroll
    for (int m = 0; m < 4; ++m)
        #pragma unroll
        for (int n = 0; n < 4; ++n)
            #pragma unroll
            for (int r = 0; r < 4; ++r)
                P[h][m * 16 + kh * 4 + r][n * 16 + lr] = f2bf(acc[m][n][r]);
    __syncthreads();
    // PV
    f32x4 oacc[4][2];
    #pragma unroll
    for (int m = 0; m < 4; ++m) { oacc[m][0] = (f32x4){0.f,0.f,0.f,0.f}; oacc[m][1] = (f32x4){0.f,0.f,0.f,0.f}; }
    #pragma unroll
    for (int ks = 0; ks < 2; ++ks) {
        int k0 = ks * 32;
        bf16x8 ap[4], bv[2];
        #pragma unroll
        for (int m = 0; m < 4; ++m) ap[m] = *(const bf16x8*)(&P[h][m * 16 + lr][k0 + kh * 8]);
        #pragma unroll
        for (int n = 0; n < 2; ++n) bv[n] = *(const bf16x8*)(&vT[h][n * 16 + lr][k0 + kh * 8]);
        #pragma unroll
        for (int m = 0; m < 4; ++m)
            #pragma unroll
            for (int n = 0; n < 2; ++n)
                oacc[m][n] = __builtin_amdgcn_mfma_f32_16x16x32_bf16(ap[m], bv[n], oacc[m][n], 0, 0, 0);
    }
    #pragma unroll
    for (int m = 0; m < 4; ++m)
        #pragma unroll
        for (int n = 0; n < 2; ++n)
            #pragma unroll
            for (int r = 0; r < 4; ++r) {
                int tok = m * 16 + kh * 4 + r;
                int d = n * 16 + lr;
                a_out[((size_t)win * 64 + tok) * 96 + h * 32 + d] = f2bf(oacc[m][n][r]);
            }
}

// ---------------- K4: out-proj + unshift + residual -> x1 (stored in d_out) ----------------
__global__ __launch_bounds__(384) void proj_res_kernel(const unsigned short* __restrict__ a_out,
                                                       const unsigned short* __restrict__ wo_t,
                                                       const float* __restrict__ b_out,
                                                       const float* __restrict__ x,
                                                       float* __restrict__ x1) {
    int win = blockIdx.x;
    int wave = threadIdx.x >> 6;
    int lane = threadIdx.x & 63;
    int lr = lane & 15, kh = lane >> 4;
    int n0 = wave * 16;
    f32x4 acc[4];
    #pragma unroll
    for (int m = 0; m < 4; ++m) acc[m] = (f32x4){0.f, 0.f, 0.f, 0.f};
    #pragma unroll
    for (int ks = 0; ks < 3; ++ks) {
        int k0 = ks * 32;
        bf16x8 bb = *(const bf16x8*)(wo_t + (size_t)(n0 + lr) * 96 + k0 + kh * 8);
        #pragma unroll
        for (int m = 0; m < 4; ++m) {
            bf16x8 a = *(const bf16x8*)(a_out + ((size_t)win * 64 + m * 16 + lr) * 96 + k0 + kh * 8);
            acc[m] = __builtin_amdgcn_mfma_f32_16x16x32_bf16(a, bb, acc[m], 0, 0, 0);
        }
    }
    int ix = win >> 8, iy = (win >> 4) & 15, iz = win & 15;
    int c = n0 + lr;
    float bo = b_out[c];
    #pragma unroll
    for (int m = 0; m < 4; ++m)
        #pragma unroll
        for (int r = 0; r < 4; ++r) {
            int tok = m * 16 + kh * 4 + r;
            int wx = tok >> 4, wy = (tok >> 2) & 3, wz = tok & 3;
            int px = (ix * 4 + wx + 2) & 63;   // roll back (+2)
            int py = (iy * 4 + wy + 2) & 63;
            int pz = (iz * 4 + wz + 2) & 63;
            size_t o = ((size_t)((px * 64 + py) * 64 + pz)) * 96 + c;
            x1[o] = x[o] + acc[m][r] + bo;
        }
}

// ---------------- K5: fused LN2 + MLP1 + GELU + MLP2 + residual (in-place on d_out) ----------------
__global__ __launch_bounds__(384) void mlp_kernel(float* __restrict__ xio,
                                                  const float* __restrict__ g2, const float* __restrict__ bt2,
                                                  const unsigned short* __restrict__ w1_t, const float* __restrict__ b1,
                                                  const unsigned short* __restrict__ w2_t, const float* __restrict__ b2) {
    __shared__ __align__(16) unsigned short xl[64][104];
    __shared__ __align__(16) unsigned short gl[64][392];
    int tile = blockIdx.x;
    int tid = threadIdx.x;
    int wave = tid >> 6, lane = tid & 63;
    int lr = lane & 15, kh = lane >> 4;
    // LN2 into LDS (bf16)
    {
        int grp = tid >> 5;      // 0..11
        int gi = tid & 31;
        for (int t = grp; t < 64; t += 12) {
            size_t src = ((size_t)tile * 64 + t) * 96;
            float v0 = xio[src + gi], v1 = xio[src + 32 + gi], v2 = xio[src + 64 + gi];
            float s = v0 + v1 + v2, sq = v0 * v0 + v1 * v1 + v2 * v2;
            #pragma unroll
            for (int m = 16; m >= 1; m >>= 1) { s += __shfl_xor(s, m, 32); sq += __shfl_xor(sq, m, 32); }
            float mean = s * (1.0f / 96.0f);
            float var = sq * (1.0f / 96.0f) - mean * mean;
            float rstd = rsqrtf(var + 1e-5f);
            xl[t][gi]      = f2bf((v0 - mean) * rstd * g2[gi]      + bt2[gi]);
            xl[t][gi + 32] = f2bf((v1 - mean) * rstd * g2[gi + 32] + bt2[gi + 32]);
            xl[t][gi + 64] = f2bf((v2 - mean) * rstd * g2[gi + 64] + bt2[gi + 64]);
        }
    }
    __syncthreads();
    // GEMM1 (96 -> 384) + GELU -> gl
    {
        f32x4 acc[4][4];
        #pragma unroll
        for (int m = 0; m < 4; ++m)
            #pragma unroll
            for (int n = 0; n < 4; ++n) acc[m][n] = (f32x4){0.f, 0.f, 0.f, 0.f};
        #pragma unroll
        for (int ks = 0; ks < 3; ++ks) {
            int k0 = ks * 32;
            bf16x8 a[4], bb[4];
            #pragma unroll
            for (int m = 0; m < 4; ++m) a[m] = *(const bf16x8*)(&xl[m * 16 + lr][k0 + kh * 8]);
            #pragma unroll
            for (int n = 0; n < 4; ++n)
                bb[n] = *(const bf16x8*)(w1_t + (size_t)(wave * 64 + n * 16 + lr) * 96 + k0 + kh * 8);
            #pragma unroll
            for (int m = 0; m < 4; ++m)
                #pragma unroll
                for (int n = 0; n < 4; ++n)
                    acc[m][n] = __builtin_amdgcn_mfma_f32_16x16x32_bf16(a[m], bb[n], acc[m][n], 0, 0, 0);
        }
        #pragma unroll
        for (int n = 0; n < 4; ++n) {
            int col = wave * 64 + n * 16 + lr;
            float bias = b1[col];
            #pragma unroll
            for (int m = 0; m < 4; ++m)
                #pragma unroll
                for (int r = 0; r < 4; ++r) {
                    float u = acc[m][n][r] + bias;
                    float ge = 0.5f * u * (1.0f + erff(u * 0.70710678118654752f));
                    gl[m * 16 + kh * 4 + r][col] = f2bf(ge);
                }
        }
    }
    __syncthreads();
    // GEMM2 (384 -> 96) + residual
    {
        f32x4 acc2[4];
        #pragma unroll
        for (int m = 0; m < 4; ++m) acc2[m] = (f32x4){0.f, 0.f, 0.f, 0.f};
        int n0 = wave * 16;
        #pragma unroll
        for (int ks = 0; ks < 12; ++ks) {
            int k0 = ks * 32;
            bf16x8 bb = *(const bf16x8*)(w2_t + (size_t)(n0 + lr) * 384 + k0 + kh * 8);
            #pragma unroll
            for (int m = 0; m < 4; ++m) {
                bf16x8 a = *(const bf16x8*)(&gl[m * 16 + lr][k0 + kh * 8]);
                acc2[m] = __builtin_amdgcn_mfma_f32_16x16x32_bf16(a, bb, acc2[m], 0, 0, 0);
            }
        }
        int c = n0 + lr;
        float bias = b2[c];
        #pragma unroll
        for (int m = 0; m < 4; ++m)
            #pragma unroll
            for (int r = 0; r < 4; ++r) {
                int row = m * 16 + kh * 4 + r;
                size_t o = ((size_t)tile * 64 + row) * 96 + c;
                xio[o] = xio[o] + acc2[m][r] + bias;
            }
    }
}

extern "C" void kernel_launch(void* const* d_in, const int* in_sizes, int n_in,
                              void* d_out, int out_size, void* d_ws, size_t ws_size,
                              hipStream_t stream) {
    const float* x       = (const float*)d_in[0];
    const float* Wqkv    = (const float*)d_in[1];
    const float* Wout    = (const float*)d_in[2];
    const float* b_out   = (const float*)d_in[3];
    const float* pos_tab = (const float*)d_in[4];
    const float* ln1_g   = (const float*)d_in[5];
    const float* ln1_b   = (const float*)d_in[6];
    const float* ln2_g   = (const float*)d_in[7];
    const float* ln2_b   = (const float*)d_in[8];
    const float* W1      = (const float*)d_in[9];
    const float* b1      = (const float*)d_in[10];
    const float* W2      = (const float*)d_in[11];
    const float* b2      = (const float*)d_in[12];
    float* out = (float*)d_out;

    char* ws = (char*)d_ws;
    unsigned short* y    = (unsigned short*)(ws);                         // 48 MB (LN1 out; later aliased by a_out)
    unsigned short* qkv  = (unsigned short*)(ws + 50331648);              // 144 MB
    unsigned short* wq_t = (unsigned short*)(ws + 50331648 + 150994944);  // 55296 B
    unsigned short* wo_t = wq_t + 27648;                                  // 18432 B
    unsigned short* w1_t = wo_t + 9216;                                   // 73728 B
    unsigned short* w2_t = w1_t + 36864;                                  // 73728 B
    unsigned short* a_out = y;   // y is dead after the QKV GEMM

    convert_weights<<<432, 256, 0, stream>>>(Wqkv, Wout, W1, W2, wq_t, wo_t, w1_t, w2_t);
    ln1_shift_kernel<<<32768, 256, 0, stream>>>(x, ln1_g, ln1_b, y);
    qkv_gemm_kernel<<<NWIN, 384, 0, stream>>>(y, wq_t, qkv);
    attn_kernel<<<NWIN, 192, 0, stream>>>(qkv, pos_tab, a_out);
    proj_res_kernel<<<NWIN, 384, 0, stream>>>(a_out, wo_t, b_out, x, out);
    mlp_kernel<<<NWIN, 384, 0, stream>>>(out, ln2_g, ln2_b, w1_t, b1, w2_t, b2);
}

// Round 2
// 330.965 us; speedup vs baseline: 1.2760x; 1.2760x over previous
//
#include <hip/hip_runtime.h>

typedef __attribute__((ext_vector_type(8))) short bf16x8;
typedef __attribute__((ext_vector_type(4))) float f32x4;

#define NTOK 262144   // 64^3 tokens
#define NWIN 4096     // 16^3 windows of 4^3

__device__ __forceinline__ unsigned short f2bf(float f) {
    unsigned int u = __float_as_uint(f);
    unsigned int r = (u + 0x7FFFu + ((u >> 16) & 1u)) >> 16;
    return (unsigned short)r;
}
__device__ __forceinline__ int region(int g) { return (g >= 60) + (g >= 62); }

// ---------------- K0: weight convert + transpose to N-major bf16 ----------------
__global__ void convert_weights(const float* __restrict__ Wqkv, const float* __restrict__ Wout,
                                const float* __restrict__ W1, const float* __restrict__ W2,
                                unsigned short* __restrict__ wq_t, unsigned short* __restrict__ wo_t,
                                unsigned short* __restrict__ w1_t, unsigned short* __restrict__ w2_t) {
    int idx = blockIdx.x * blockDim.x + threadIdx.x;
    if (idx < 27648) {                       // wq_t[288][96] = Wqkv[96][288]^T
        int n = idx / 96, k = idx % 96;
        wq_t[idx] = f2bf(Wqkv[k * 288 + n]);
    } else if (idx < 27648 + 9216) {         // wo_t[96][96]
        int i = idx - 27648; int n = i / 96, k = i % 96;
        wo_t[i] = f2bf(Wout[k * 96 + n]);
    } else if (idx < 27648 + 9216 + 36864) { // w1_t[384][96]
        int i = idx - 36864; int n = i / 96, k = i % 96;
        w1_t[i] = f2bf(W1[k * 384 + n]);
    } else if (idx < 110592) {               // w2_t[96][384]
        int i = idx - 73728; int n = i / 384, k = i % 384;
        w2_t[i] = f2bf(W2[k * 96 + n]);
    }
}

// ---------------- K1: LN1 + cyclic shift(-2) + window-major relayout ----------------
__global__ __launch_bounds__(256) void ln1_shift_kernel(const float* __restrict__ x,
                                                        const float* __restrict__ g,
                                                        const float* __restrict__ b,
                                                        unsigned short* __restrict__ y) {
    int tid = blockIdx.x * blockDim.x + threadIdx.x;
    int token = tid >> 5;          // output (shifted-frame) token
    int lane = tid & 31;
    if (token >= NTOK) return;
    int pz = token & 63, py = (token >> 6) & 63, px = token >> 12;
    int sx = (px + 2) & 63, sy = (py + 2) & 63, sz = (pz + 2) & 63;   // roll(x,-2)
    size_t src = ((size_t)((sx * 64 + sy) * 64 + sz)) * 96;
    float v0 = x[src + lane], v1 = x[src + 32 + lane], v2 = x[src + 64 + lane];
    float s = v0 + v1 + v2;
    float sq = v0 * v0 + v1 * v1 + v2 * v2;
    #pragma unroll
    for (int m = 16; m >= 1; m >>= 1) { s += __shfl_xor(s, m, 32); sq += __shfl_xor(sq, m, 32); }
    float mean = s * (1.0f / 96.0f);
    float var = sq * (1.0f / 96.0f) - mean * mean;
    float rstd = rsqrtf(var + 1e-5f);
    int win = ((px >> 2) * 16 + (py >> 2)) * 16 + (pz >> 2);
    int loc = ((px & 3) * 4 + (py & 3)) * 4 + (pz & 3);
    size_t dst = ((size_t)(win * 64 + loc)) * 96;
    y[dst + lane]      = f2bf((v0 - mean) * rstd * g[lane]      + b[lane]);
    y[dst + 32 + lane] = f2bf((v1 - mean) * rstd * g[lane + 32] + b[lane + 32]);
    y[dst + 64 + lane] = f2bf((v2 - mean) * rstd * g[lane + 64] + b[lane + 64]);
}

// ---------------- K2: QKV GEMM  [262144,96] x [96,288] -> qkv[win][qq][h][tok][32] bf16 ----------------
__global__ __launch_bounds__(384) void qkv_gemm_kernel(const unsigned short* __restrict__ y,
                                                       const unsigned short* __restrict__ wq_t,
                                                       unsigned short* __restrict__ qkv) {
    int win = blockIdx.x;
    int wave = threadIdx.x >> 6;
    int lane = threadIdx.x & 63;
    int lr = lane & 15, kh = lane >> 4;
    f32x4 acc[4][3];
    #pragma unroll
    for (int m = 0; m < 4; ++m)
        #pragma unroll
        for (int n = 0; n < 3; ++n) acc[m][n] = (f32x4){0.f, 0.f, 0.f, 0.f};
    #pragma unroll
    for (int ks = 0; ks < 3; ++ks) {
        int k0 = ks * 32;
        bf16x8 a[4], bb[3];
        #pragma unroll
        for (int m = 0; m < 4; ++m)
            a[m] = *(const bf16x8*)(y + ((size_t)win * 64 + m * 16 + lr) * 96 + k0 + kh * 8);
        #pragma unroll
        for (int n = 0; n < 3; ++n)
            bb[n] = *(const bf16x8*)(wq_t + ((size_t)(wave * 48 + n * 16 + lr)) * 96 + k0 + kh * 8);
        #pragma unroll
        for (int m = 0; m < 4; ++m)
            #pragma unroll
            for (int n = 0; n < 3; ++n)
                acc[m][n] = __builtin_amdgcn_mfma_f32_16x16x32_bf16(a[m], bb[n], acc[m][n], 0, 0, 0);
    }
    #pragma unroll
    for (int n = 0; n < 3; ++n) {
        int c = wave * 48 + n * 16 + lr;
        int qq = c / 96, rem = c % 96;
        int h = rem >> 5, d = rem & 31;
        size_t base = (((size_t)win * 3 + qq) * 3 + h) * 2048 + d;
        #pragma unroll
        for (int m = 0; m < 4; ++m)
            #pragma unroll
            for (int r = 0; r < 4; ++r) {
                int tok = m * 16 + kh * 4 + r;
                qkv[base + (size_t)tok * 32] = f2bf(acc[m][n][r]);
            }
    }
}

// ---------------- K3: per-window attention ----------------
__global__ __launch_bounds__(192) void attn_kernel(const unsigned short* __restrict__ qkv,
                                                   const float* __restrict__ pos_tab,
                                                   unsigned short* __restrict__ a_out) {
    __shared__ __align__(16) float pos[344];
    __shared__ __align__(16) unsigned short vT[3][32][72];
    __shared__ __align__(16) unsigned short P[3][64][72];
    int win = blockIdx.x;
    int h = threadIdx.x >> 6;
    int lane = threadIdx.x & 63;
    int lr = lane & 15, kh = lane >> 4;
    for (int i = threadIdx.x; i < 343; i += 192) pos[i] = pos_tab[i];
    // load V transposed into LDS
    size_t vbase = (((size_t)win * 3 + 2) * 3 + h) * 2048;
    #pragma unroll
    for (int i = 0; i < 8; ++i) {
        int e0 = i * 256 + lane * 4;
        int tok = e0 >> 5, d = e0 & 31;
        const unsigned short* p = qkv + vbase + e0;
        vT[h][d + 0][tok] = p[0]; vT[h][d + 1][tok] = p[1];
        vT[h][d + 2][tok] = p[2]; vT[h][d + 3][tok] = p[3];
    }
    __syncthreads();
    // QK^T
    size_t qbase = (((size_t)win * 3 + 0) * 3 + h) * 2048;
    size_t kbase = (((size_t)win * 3 + 1) * 3 + h) * 2048;
    f32x4 acc[4][4];
    #pragma unroll
    for (int m = 0; m < 4; ++m)
        #pragma unroll
        for (int n = 0; n < 4; ++n) acc[m][n] = (f32x4){0.f, 0.f, 0.f, 0.f};
    bf16x8 aq[4], bk[4];
    #pragma unroll
    for (int m = 0; m < 4; ++m) aq[m] = *(const bf16x8*)(qkv + qbase + (m * 16 + lr) * 32 + kh * 8);
    #pragma unroll
    for (int n = 0; n < 4; ++n) bk[n] = *(const bf16x8*)(qkv + kbase + (n * 16 + lr) * 32 + kh * 8);
    #pragma unroll
    for (int m = 0; m < 4; ++m)
        #pragma unroll
        for (int n = 0; n < 4; ++n)
            acc[m][n] = __builtin_amdgcn_mfma_f32_16x16x32_bf16(aq[m], bk[n], acc[m][n], 0, 0, 0);
    // scale + relative-position bias + shifted-window mask
    int ix = win >> 8, iy = (win >> 4) & 15, iz = win & 15;
    const float scale = 0.17677669529663689f;  // 32^-0.5
    #pragma unroll
    for (int n = 0; n < 4; ++n) {
        int j = n * 16 + lr;
        int jwx = j >> 4, jwy = (j >> 2) & 3, jwz = j & 3;
        int labj = 9 * region(ix * 4 + jwx) + 3 * region(iy * 4 + jwy) + region(iz * 4 + jwz);
        #pragma unroll
        for (int m = 0; m < 4; ++m)
            #pragma unroll
            for (int r = 0; r < 4; ++r) {
                int i = m * 16 + kh * 4 + r;
                int iwx = i >> 4, iwy = (i >> 2) & 3, iwz = i & 3;
                int labi = 9 * region(ix * 4 + iwx) + 3 * region(iy * 4 + iwy) + region(iz * 4 + iwz);
                float bias = pos[((iwx - jwx + 3) * 7 + (iwy - jwy + 3)) * 7 + (iwz - jwz + 3)];
                acc[m][n][r] = acc[m][n][r] * scale + bias + (labi != labj ? -1e9f : 0.0f);
            }
    }
    // softmax over rows (row lives in 16 lanes x 4 n-frags)
    #pragma unroll
    for (int m = 0; m < 4; ++m)
        #pragma unroll
        for (int r = 0; r < 4; ++r) {
            float mx = fmaxf(fmaxf(acc[m][0][r], acc[m][1][r]), fmaxf(acc[m][2][r], acc[m][3][r]));
            #pragma unroll
            for (int s = 1; s < 16; s <<= 1) mx = fmaxf(mx, __shfl_xor(mx, s, 16));
            float e0 = __expf(acc[m][0][r] - mx), e1 = __expf(acc[m][1][r] - mx);
            float e2 = __expf(acc[m][2][r] - mx), e3 = __expf(acc[m][3][r] - mx);
            float sum = e0 + e1 + e2 + e3;
            #pragma unroll
            for (int s = 1; s < 16; s <<= 1) sum += __shfl_xor(sum, s, 16);
            float rs = 1.0f / sum;
            acc[m][0][r] = e0 * rs; acc[m][1][r] = e1 * rs;
            acc[m][2][r] = e2 * rs; acc[m][3][r] = e3 * rs;
        }
    // write P to LDS (bf16)
    #pragma unroll
    for (int m = 0; m < 4; ++m)
        #pragma unroll
        for (int n = 0; n < 4; ++n)
            #pragma unroll
            for (int r = 0; r < 4; ++r)
                P[h][m * 16 + kh * 4 + r][n * 16 + lr] = f2bf(acc[m][n][r]);
    __syncthreads();
    // PV
    f32x4 oacc[4][2];
    #pragma unroll
    for (int m = 0; m < 4; ++m) { oacc[m][0] = (f32x4){0.f,0.f,0.f,0.f}; oacc[m][1] = (f32x4){0.f,0.f,0.f,0.f}; }
    #pragma unroll
    for (int ks = 0; ks < 2; ++ks) {
        int k0 = ks * 32;
        bf16x8 ap[4], bv[2];
        #pragma unroll
        for (int m = 0; m < 4; ++m) ap[m] = *(const bf16x8*)(&P[h][m * 16 + lr][k0 + kh * 8]);
        #pragma unroll
        for (int n = 0; n < 2; ++n) bv[n] = *(const bf16x8*)(&vT[h][n * 16 + lr][k0 + kh * 8]);
        #pragma unroll
        for (int m = 0; m < 4; ++m)
            #pragma unroll
            for (int n = 0; n < 2; ++n)
                oacc[m][n] = __builtin_amdgcn_mfma_f32_16x16x32_bf16(ap[m], bv[n], oacc[m][n], 0, 0, 0);
    }
    #pragma unroll
    for (int m = 0; m < 4; ++m)
        #pragma unroll
        for (int n = 0; n < 2; ++n)
            #pragma unroll
            for (int r = 0; r < 4; ++r) {
                int tok = m * 16 + kh * 4 + r;
                int d = n * 16 + lr;
                a_out[((size_t)win * 64 + tok) * 96 + h * 32 + d] = f2bf(oacc[m][n][r]);
            }
}

// ---------------- K4: FUSED proj + residual + LN2 + MLP + residual ----------------
// One block per window (384 thr). Proj result + residual kept in LDS (xf, fp32);
// LN2 -> xl (bf16); MLP chunked over hidden dim in 4 slices of 96 so the GELU
// buffer is only [64][104] bf16. LDS total ~52 KB -> 3 blocks/CU.
__global__ __launch_bounds__(384) void proj_mlp_kernel(const unsigned short* __restrict__ a_out,
                                                       const unsigned short* __restrict__ wo_t,
                                                       const float* __restrict__ b_out,
                                                       const float* __restrict__ x,
                                                       const float* __restrict__ g2, const float* __restrict__ bt2,
                                                       const unsigned short* __restrict__ w1_t, const float* __restrict__ b1,
                                                       const unsigned short* __restrict__ w2_t, const float* __restrict__ b2,
                                                       float* __restrict__ out) {
    __shared__ __align__(16) float xf[64][100];          // x1 = x + proj + b_out (fp32 residual)
    __shared__ __align__(16) unsigned short xl[64][104]; // LN2(x1), bf16
    __shared__ __align__(16) unsigned short gl[64][104]; // GELU chunk, bf16
    int win = blockIdx.x;
    int wave = threadIdx.x >> 6;
    int lane = threadIdx.x & 63;
    int lr = lane & 15, kh = lane >> 4;
    int ix = win >> 8, iy = (win >> 4) & 15, iz = win & 15;
    int c = wave * 16 + lr;    // this thread's output channel (0..95)

    // ---- attention out-projection: 96x96 GEMM over this window's 64 tokens ----
    f32x4 acc[4];
    #pragma unroll
    for (int m = 0; m < 4; ++m) acc[m] = (f32x4){0.f, 0.f, 0.f, 0.f};
    #pragma unroll
    for (int ks = 0; ks < 3; ++ks) {
        int k0 = ks * 32;
        bf16x8 bb = *(const bf16x8*)(wo_t + (size_t)c * 96 + k0 + kh * 8);
        #pragma unroll
        for (int m = 0; m < 4; ++m) {
            bf16x8 a = *(const bf16x8*)(a_out + ((size_t)win * 64 + m * 16 + lr) * 96 + k0 + kh * 8);
            acc[m] = __builtin_amdgcn_mfma_f32_16x16x32_bf16(a, bb, acc[m], 0, 0, 0);
        }
    }
    float bo = b_out[c];
    #pragma unroll
    for (int m = 0; m < 4; ++m)
        #pragma unroll
        for (int r = 0; r < 4; ++r) {
            int tok = m * 16 + kh * 4 + r;
            int wx = tok >> 4, wy = (tok >> 2) & 3, wz = tok & 3;
            int px = (ix * 4 + wx + 2) & 63;   // unshift (+2)
            int py = (iy * 4 + wy + 2) & 63;
            int pz = (iz * 4 + wz + 2) & 63;
            size_t o = ((size_t)((px * 64 + py) * 64 + pz)) * 96 + c;
            xf[tok][c] = x[o] + acc[m][r] + bo;
        }
    __syncthreads();

    // ---- LN2 from LDS ----
    {
        int grp = threadIdx.x >> 5;   // 0..11
        int gi = threadIdx.x & 31;
        for (int t = grp; t < 64; t += 12) {
            float v0 = xf[t][gi], v1 = xf[t][gi + 32], v2 = xf[t][gi + 64];
            float s = v0 + v1 + v2, sq = v0 * v0 + v1 * v1 + v2 * v2;
            #pragma unroll
            for (int m = 16; m >= 1; m >>= 1) { s += __shfl_xor(s, m, 32); sq += __shfl_xor(sq, m, 32); }
            float mean = s * (1.0f / 96.0f);
            float var = sq * (1.0f / 96.0f) - mean * mean;
            float rstd = rsqrtf(var + 1e-5f);
            xl[t][gi]      = f2bf((v0 - mean) * rstd * g2[gi]      + bt2[gi]);
            xl[t][gi + 32] = f2bf((v1 - mean) * rstd * g2[gi + 32] + bt2[gi + 32]);
            xl[t][gi + 64] = f2bf((v2 - mean) * rstd * g2[gi + 64] + bt2[gi + 64]);
        }
    }
    __syncthreads();

    // ---- MLP, chunked over hidden dim (4 chunks x 96) ----
    int wm = wave & 1;        // 2 m-groups of 32 tokens
    int wn = wave >> 1;       // 3 n-groups of 32 chunk-cols
    f32x4 acc2[4];
    #pragma unroll
    for (int m = 0; m < 4; ++m) acc2[m] = (f32x4){0.f, 0.f, 0.f, 0.f};
    for (int ch = 0; ch < 4; ++ch) {
        // GEMM1 chunk: [64 tok] x [96 cols], waves in 2x3 grid, 2x2 frags each
        f32x4 a1[2][2];
        #pragma unroll
        for (int mf = 0; mf < 2; ++mf)
            #pragma unroll
            for (int nf = 0; nf < 2; ++nf) a1[mf][nf] = (f32x4){0.f, 0.f, 0.f, 0.f};
        #pragma unroll
        for (int ks = 0; ks < 3; ++ks) {
            int k0 = ks * 32;
            bf16x8 af[2], bf[2];
            #pragma unroll
            for (int mf = 0; mf < 2; ++mf)
                af[mf] = *(const bf16x8*)(&xl[wm * 32 + mf * 16 + lr][k0 + kh * 8]);
            #pragma unroll
            for (int nf = 0; nf < 2; ++nf)
                bf[nf] = *(const bf16x8*)(w1_t + (size_t)(ch * 96 + wn * 32 + nf * 16 + lr) * 96 + k0 + kh * 8);
            #pragma unroll
            for (int mf = 0; mf < 2; ++mf)
                #pragma unroll
                for (int nf = 0; nf < 2; ++nf)
                    a1[mf][nf] = __builtin_amdgcn_mfma_f32_16x16x32_bf16(af[mf], bf[nf], a1[mf][nf], 0, 0, 0);
        }
        #pragma unroll
        for (int nf = 0; nf < 2; ++nf) {
            int col = wn * 32 + nf * 16 + lr;
            float bias = b1[ch * 96 + col];
            #pragma unroll
            for (int mf = 0; mf < 2; ++mf)
                #pragma unroll
                for (int r = 0; r < 4; ++r) {
                    float u = a1[mf][nf][r] + bias;
                    float ge = 0.5f * u * (1.0f + erff(u * 0.70710678118654752f));
                    gl[wm * 32 + mf * 16 + kh * 4 + r][col] = f2bf(ge);
                }
        }
        __syncthreads();
        // GEMM2 partial: K-slice = this chunk's 96 cols
        #pragma unroll
        for (int kc = 0; kc < 3; ++kc) {
            int k0 = kc * 32;
            bf16x8 bb = *(const bf16x8*)(w2_t + (size_t)c * 384 + ch * 96 + k0 + kh * 8);
            #pragma unroll
            for (int m = 0; m < 4; ++m) {
                bf16x8 a = *(const bf16x8*)(&gl[m * 16 + lr][k0 + kh * 8]);
                acc2[m] = __builtin_amdgcn_mfma_f32_16x16x32_bf16(a, bb, acc2[m], 0, 0, 0);
            }
        }
        __syncthreads();
    }

    // ---- final residual write ----
    float bias2 = b2[c];
    #pragma unroll
    for (int m = 0; m < 4; ++m)
        #pragma unroll
        for (int r = 0; r < 4; ++r) {
            int tok = m * 16 + kh * 4 + r;
            int wx = tok >> 4, wy = (tok >> 2) & 3, wz = tok & 3;
            int px = (ix * 4 + wx + 2) & 63;
            int py = (iy * 4 + wy + 2) & 63;
            int pz = (iz * 4 + wz + 2) & 63;
            size_t o = ((size_t)((px * 64 + py) * 64 + pz)) * 96 + c;
            out[o] = xf[tok][c] + acc2[m][r] + bias2;
        }
}

extern "C" void kernel_launch(void* const* d_in, const int* in_sizes, int n_in,
                              void* d_out, int out_size, void* d_ws, size_t ws_size,
                              hipStream_t stream) {
    const float* x       = (const float*)d_in[0];
    const float* Wqkv    = (const float*)d_in[1];
    const float* Wout    = (const float*)d_in[2];
    const float* b_out   = (const float*)d_in[3];
    const float* pos_tab = (const float*)d_in[4];
    const float* ln1_g   = (const float*)d_in[5];
    const float* ln1_b   = (const float*)d_in[6];
    const float* ln2_g   = (const float*)d_in[7];
    const float* ln2_b   = (const float*)d_in[8];
    const float* W1      = (const float*)d_in[9];
    const float* b1      = (const float*)d_in[10];
    const float* W2      = (const float*)d_in[11];
    const float* b2      = (const float*)d_in[12];
    float* out = (float*)d_out;

    char* ws = (char*)d_ws;
    unsigned short* y    = (unsigned short*)(ws);                         // 48 MB (LN1 out; later aliased by a_out)
    unsigned short* qkv  = (unsigned short*)(ws + 50331648);              // 144 MB
    unsigned short* wq_t = (unsigned short*)(ws + 50331648 + 150994944);  // 55296 B
    unsigned short* wo_t = wq_t + 27648;                                  // 18432 B
    unsigned short* w1_t = wo_t + 9216;                                   // 73728 B
    unsigned short* w2_t = w1_t + 36864;                                  // 73728 B
    unsigned short* a_out = y;   // y is dead after the QKV GEMM

    convert_weights<<<432, 256, 0, stream>>>(Wqkv, Wout, W1, W2, wq_t, wo_t, w1_t, w2_t);
    ln1_shift_kernel<<<32768, 256, 0, stream>>>(x, ln1_g, ln1_b, y);
    qkv_gemm_kernel<<<NWIN, 384, 0, stream>>>(y, wq_t, qkv);
    attn_kernel<<<NWIN, 192, 0, stream>>>(qkv, pos_tab, a_out);
    proj_mlp_kernel<<<NWIN, 384, 0, stream>>>(a_out, wo_t, b_out, x,
                                              ln2_g, ln2_b, w1_t, b1, w2_t, b2, out);
}